// Round 2
// baseline (7162.533 us; speedup 1.0000x reference)
//
#include <hip/hip_runtime.h>

#define T_STEPS 8192
#define BATCH   128
#define HID     96

// ---- weight registers: 24 NAMED float4 (SROA-proof; R0's float[] went to scratch, VGPR=44) ----
#define WDECL(n) const float4 w##n = wr4[n];
// one 4-element chunk of the 96-dot, accumulating into A
#define HSTEP(n, A) { const float4 hh = hv[n]; \
    A = fmaf(hh.x, w##n.x, A); A = fmaf(hh.y, w##n.y, A); \
    A = fmaf(hh.z, w##n.z, A); A = fmaf(hh.w, w##n.w, A); }

__global__ __launch_bounds__(448, 2)
void lstm_seq_kernel(const float* __restrict__ x,
                     const float* __restrict__ W_ih,
                     const float* __restrict__ W_hh,
                     const float* __restrict__ b_ih,
                     const float* __restrict__ b_hh,
                     const float* __restrict__ W_fc,
                     const float* __restrict__ b_fc,
                     float* __restrict__ out)
{
    const int b   = blockIdx.x;
    const int tid = threadIdx.x;   // 0..447 (7 waves: 6 dot waves + 1 FC wave)

    __shared__ __align__(16) float h_buf[2][HID];   // double-buffered hidden state

    if (tid < HID) { h_buf[0][tid] = 0.0f; h_buf[1][tid] = 0.0f; }
    __syncthreads();

    if (tid < 384) {
        // ---------------- dot waves: one (hidden j, gate r) per thread ----------------
        const int j   = tid >> 2;      // 0..95
        const int r   = tid & 3;       // 0=i 1=f 2=g 3=o  (quad-local)
        const int row = r * HID + j;   // W_hh row

        const float4* wr4 = reinterpret_cast<const float4*>(W_hh + row * HID);
        WDECL(0)  WDECL(1)  WDECL(2)  WDECL(3)  WDECL(4)  WDECL(5)
        WDECL(6)  WDECL(7)  WDECL(8)  WDECL(9)  WDECL(10) WDECL(11)
        WDECL(12) WDECL(13) WDECL(14) WDECL(15) WDECL(16) WDECL(17)
        WDECL(18) WDECL(19) WDECL(20) WDECL(21) WDECL(22) WDECL(23)

        const float wih  = W_ih[row];
        const float bsum = b_ih[row] + b_hh[row];
        float c  = 0.0f;                 // redundant per quad (bitwise identical)
        float xt = x[0 * BATCH + b];

        for (int t = 0; t < T_STEPS; ++t) {
            const int   tn    = (t + 1 < T_STEPS) ? (t + 1) : t;
            const float xnext = x[tn * BATCH + b];          // prefetch, uniform load

            const float4* hv = reinterpret_cast<const float4*>(h_buf[t & 1]);
            float a0 = fmaf(xt, wih, bsum), a1 = 0.f, a2 = 0.f, a3 = 0.f;
            HSTEP(0,a0)  HSTEP(1,a1)  HSTEP(2,a2)  HSTEP(3,a3)
            HSTEP(4,a0)  HSTEP(5,a1)  HSTEP(6,a2)  HSTEP(7,a3)
            HSTEP(8,a0)  HSTEP(9,a1)  HSTEP(10,a2) HSTEP(11,a3)
            HSTEP(12,a0) HSTEP(13,a1) HSTEP(14,a2) HSTEP(15,a3)
            HSTEP(16,a0) HSTEP(17,a1) HSTEP(18,a2) HSTEP(19,a3)
            HSTEP(20,a0) HSTEP(21,a1) HSTEP(22,a2) HSTEP(23,a3)
            const float acc = (a0 + a1) + (a2 + a3);

            // activation: sigmoid for i,f,o; tanh for g  (tanh(x)=2*sigmoid(2x)-1)
            const float pre = (r == 2) ? (acc + acc) : acc;
            const float sg  = __builtin_amdgcn_rcpf(1.0f + __expf(-pre));
            const float a   = (r == 2) ? fmaf(2.0f, sg, -1.0f) : sg;

            // quad gather: L0=i L1=f L2=g L3=o  ->  c_new = i*g + f*c in all 4 lanes
            const float v1   = __shfl_xor(a, 2);            // i<->g, f<->o
            const float fval = (r == 1) ? a : v1;           // f available on odd lanes
            const float p    = (r & 1) ? (fval * c) : (a * v1);   // odd: f*c, even: i*g
            const float cn   = p + __shfl_xor(p, 1);
            c = cn;

            if (r == 3) {   // lane holding o computes and publishes h
                const float th = fmaf(2.0f,
                    __builtin_amdgcn_rcpf(1.0f + __expf(-2.0f * cn)), -1.0f);
                h_buf[(t & 1) ^ 1][j] = a * th;
            }
            __syncthreads();    // single barrier: publishes h_{t+1}, retires reads of buf
            xt = xnext;
        }
    } else {
        // ---------------- FC wave (wave 6): out[t-1] = h_t . W_fc + b + x[t-1] ----------------
        const int   lane = tid - 384;                       // 0..63
        const float wfa  = W_fc[lane];
        const float wfb  = (lane < 32) ? W_fc[64 + lane] : 0.0f;
        const float bfc  = b_fc[0];

        for (int t = 0; t < T_STEPS; ++t) {
            if (t > 0) {
                const float  xprev = x[(t - 1) * BATCH + b];
                const float* hb    = h_buf[t & 1];          // h_t
                float s = hb[lane] * wfa;
                if (lane < 32) s = fmaf(hb[64 + lane], wfb, s);
                #pragma unroll
                for (int d = 1; d < 64; d <<= 1) s += __shfl_xor(s, d);
                if (lane == 0) out[(t - 1) * BATCH + b] = s + bfc + xprev;
            }
            __syncthreads();
        }
        // final timestep: h_T lives in h_buf[T&1] == h_buf[0]
        {
            const float  xprev = x[(T_STEPS - 1) * BATCH + b];
            const float* hb    = h_buf[T_STEPS & 1];
            float s = hb[lane] * wfa;
            if (lane < 32) s = fmaf(hb[64 + lane], wfb, s);
            #pragma unroll
            for (int d = 1; d < 64; d <<= 1) s += __shfl_xor(s, d);
            if (lane == 0) out[(T_STEPS - 1) * BATCH + b] = s + bfc + xprev;
        }
    }
}

extern "C" void kernel_launch(void* const* d_in, const int* in_sizes, int n_in,
                              void* d_out, int out_size, void* d_ws, size_t ws_size,
                              hipStream_t stream) {
    (void)in_sizes; (void)n_in; (void)out_size; (void)d_ws; (void)ws_size;
    const float* x    = (const float*)d_in[0];
    const float* W_ih = (const float*)d_in[1];
    const float* W_hh = (const float*)d_in[2];
    const float* b_ih = (const float*)d_in[3];
    const float* b_hh = (const float*)d_in[4];
    const float* W_fc = (const float*)d_in[5];
    const float* b_fc = (const float*)d_in[6];
    float* out = (float*)d_out;

    lstm_seq_kernel<<<dim3(BATCH), dim3(448), 0, stream>>>(
        x, W_ih, W_hh, b_ih, b_hh, W_fc, b_fc, out);
}

// Round 4
// 5101.429 us; speedup vs baseline: 1.4040x; 1.4040x over previous
//
#include <hip/hip_runtime.h>

#define T_STEPS 8192
#define BATCH   128
#define HID     96

typedef __fp16 h2_t __attribute__((ext_vector_type(2)));

__device__ __forceinline__ unsigned int pk2(float a, float b) {
    return __builtin_bit_cast(unsigned int, __builtin_amdgcn_cvt_pkrtz(a, b));
}
__device__ __forceinline__ uint4 cvt8(float4 a, float4 b) {
    uint4 r;
    r.x = pk2(a.x, a.y); r.y = pk2(a.z, a.w);
    r.z = pk2(b.x, b.y); r.w = pk2(b.z, b.w);
    return r;
}
__device__ __forceinline__ float dot8(uint4 w, uint4 h, float acc) {
    acc = __builtin_amdgcn_fdot2(__builtin_bit_cast(h2_t, w.x), __builtin_bit_cast(h2_t, h.x), acc, false);
    acc = __builtin_amdgcn_fdot2(__builtin_bit_cast(h2_t, w.y), __builtin_bit_cast(h2_t, h.y), acc, false);
    acc = __builtin_amdgcn_fdot2(__builtin_bit_cast(h2_t, w.z), __builtin_bit_cast(h2_t, h.z), acc, false);
    acc = __builtin_amdgcn_fdot2(__builtin_bit_cast(h2_t, w.w), __builtin_bit_cast(h2_t, h.w), acc, false);
    return acc;
}
__device__ __forceinline__ float fast_sigmoid(float v) {
    return __builtin_amdgcn_rcpf(1.0f + __expf(-v));
}
__device__ __forceinline__ float fast_tanh(float v) {   // 2*sigmoid(2v)-1
    return fmaf(2.0f, __builtin_amdgcn_rcpf(1.0f + __expf(-2.0f * v)), -1.0f);
}

// named f16-packed weight chunks for gate g (6 x uint4 = 48 f16 = this thread's K-half)
#define WROW(g) \
    const float4* wp##g = reinterpret_cast<const float4*>(W_hh + ((g) * HID + j) * HID + p * 48); \
    const uint4 w##g##_0 = cvt8(wp##g[0],  wp##g[1]);  \
    const uint4 w##g##_1 = cvt8(wp##g[2],  wp##g[3]);  \
    const uint4 w##g##_2 = cvt8(wp##g[4],  wp##g[5]);  \
    const uint4 w##g##_3 = cvt8(wp##g[6],  wp##g[7]);  \
    const uint4 w##g##_4 = cvt8(wp##g[8],  wp##g[9]);  \
    const uint4 w##g##_5 = cvt8(wp##g[10], wp##g[11]);

#define DOT6(g, A) \
    A = dot8(w##g##_0, h0, A); A = dot8(w##g##_1, h1, A); \
    A = dot8(w##g##_2, h2, A); A = dot8(w##g##_3, h3, A); \
    A = dot8(w##g##_4, h4, A); A = dot8(w##g##_5, h5, A);

__global__ __launch_bounds__(256)
void lstm_seq_kernel(const float* __restrict__ x,
                     const float* __restrict__ W_ih,
                     const float* __restrict__ W_hh,
                     const float* __restrict__ b_ih,
                     const float* __restrict__ b_hh,
                     const float* __restrict__ W_fc,
                     const float* __restrict__ b_fc,
                     float* __restrict__ out)
{
    const int b   = blockIdx.x;
    const int tid = threadIdx.x;          // 0..255: waves 0-2 = dot workers, wave 3 = FC

    // double-buffered hidden state, f16: [buf][12 x uint4] = 96 halves each
    __shared__ __align__(16) uint4 hq[2][12];

    if (tid < 24) ((uint4*)hq)[tid] = make_uint4(0u, 0u, 0u, 0u);
    __syncthreads();

    if (tid < 192) {
        // -------- worker: unit j = tid>>1, K-half p = tid&1; owns gates i,f,g,o of j --------
        const int j = tid >> 1;
        const int p = tid & 1;

        WROW(0) WROW(1) WROW(2) WROW(3)

        const float wih0 = W_ih[0 * HID + j], bs0 = b_ih[0 * HID + j] + b_hh[0 * HID + j];
        const float wih1 = W_ih[1 * HID + j], bs1 = b_ih[1 * HID + j] + b_hh[1 * HID + j];
        const float wih2 = W_ih[2 * HID + j], bs2 = b_ih[2 * HID + j] + b_hh[2 * HID + j];
        const float wih3 = W_ih[3 * HID + j], bs3 = b_ih[3 * HID + j] + b_hh[3 * HID + j];

        float c  = 0.0f;                  // redundant across the lane pair (identical)
        float xt = x[0 * BATCH + b];

        for (int t = 0; t < T_STEPS; ++t) {
            const int   tn    = (t + 1 < T_STEPS) ? (t + 1) : t;
            const float xnext = x[tn * BATCH + b];            // uniform prefetch

            const uint4* hb = &hq[t & 1][p * 6];
            const uint4 h0 = hb[0], h1 = hb[1], h2 = hb[2];
            const uint4 h3 = hb[3], h4 = hb[4], h5 = hb[5];

            float ai = (p == 0) ? fmaf(xt, wih0, bs0) : 0.0f;
            float af = (p == 0) ? fmaf(xt, wih1, bs1) : 0.0f;
            float ag = (p == 0) ? fmaf(xt, wih2, bs2) : 0.0f;
            float ao = (p == 0) ? fmaf(xt, wih3, bs3) : 0.0f;
            DOT6(0, ai) DOT6(1, af) DOT6(2, ag) DOT6(3, ao)

            // join K-halves across the lane pair (xor-1 -> DPP quad_perm)
            const float si = ai + __shfl_xor(ai, 1);
            const float sf = af + __shfl_xor(af, 1);
            const float sg = ag + __shfl_xor(ag, 1);
            const float so = ao + __shfl_xor(ao, 1);

            const float gi = fast_sigmoid(si);
            const float gf = fast_sigmoid(sf);
            const float gg = fast_tanh(sg);
            const float go = fast_sigmoid(so);
            c = fmaf(gf, c, gi * gg);
            const float hn = go * fast_tanh(c);

            if (p == 0) ((__fp16*)&hq[(t & 1) ^ 1][0])[j] = (__fp16)hn;
            __syncthreads();
            xt = xnext;
        }
    } else {
        // -------- FC wave: out[t-1] = h_t . W_fc + b_fc + x[t-1], one step deferred --------
        const int   lane = tid - 192;
        const float wfa  = W_fc[lane];
        const float wfb  = (lane < 32) ? W_fc[64 + lane] : 0.0f;
        const float bfc  = b_fc[0];

        float xfc = x[b];                                     // x[(t-1)] for t=1
        for (int t = 0; t < T_STEPS; ++t) {
            const float xnext = x[t * BATCH + b];             // becomes xfc for iter t+1
            if (t > 0) {
                const __fp16* hh = (const __fp16*)&hq[t & 1][0];   // h_t
                float s = (float)hh[lane] * wfa;
                if (lane < 32) s = fmaf((float)hh[64 + lane], wfb, s);
                #pragma unroll
                for (int d = 1; d < 64; d <<= 1) s += __shfl_xor(s, d);
                if (lane == 0) out[(t - 1) * BATCH + b] = s + bfc + xfc;
            }
            __syncthreads();
            xfc = xnext;
        }
        {   // final timestep: h_T is in hq[T&1] (T even -> buf 0)
            const __fp16* hh = (const __fp16*)&hq[T_STEPS & 1][0];
            float s = (float)hh[lane] * wfa;
            if (lane < 32) s = fmaf((float)hh[64 + lane], wfb, s);
            #pragma unroll
            for (int d = 1; d < 64; d <<= 1) s += __shfl_xor(s, d);
            if (lane == 0) out[(T_STEPS - 1) * BATCH + b] = s + bfc + xfc;
        }
    }
}

extern "C" void kernel_launch(void* const* d_in, const int* in_sizes, int n_in,
                              void* d_out, int out_size, void* d_ws, size_t ws_size,
                              hipStream_t stream) {
    (void)in_sizes; (void)n_in; (void)out_size; (void)d_ws; (void)ws_size;
    const float* x    = (const float*)d_in[0];
    const float* W_ih = (const float*)d_in[1];
    const float* W_hh = (const float*)d_in[2];
    const float* b_ih = (const float*)d_in[3];
    const float* b_hh = (const float*)d_in[4];
    const float* W_fc = (const float*)d_in[5];
    const float* b_fc = (const float*)d_in[6];
    float* out = (float*)d_out;

    lstm_seq_kernel<<<dim3(BATCH), dim3(256), 0, stream>>>(
        x, W_ih, W_hh, b_ih, b_hh, W_fc, b_fc, out);
}

// Round 5
// 5095.671 us; speedup vs baseline: 1.4056x; 1.0011x over previous
//
#include <hip/hip_runtime.h>

#define T_STEPS 8192
#define BATCH   128
#define HID     96

typedef __fp16 h2_t __attribute__((ext_vector_type(2)));

__device__ __forceinline__ unsigned int pk2(float a, float b) {
    return __builtin_bit_cast(unsigned int, __builtin_amdgcn_cvt_pkrtz(a, b));
}
__device__ __forceinline__ uint4 cvt8(float4 a, float4 b) {
    uint4 r;
    r.x = pk2(a.x, a.y); r.y = pk2(a.z, a.w);
    r.z = pk2(b.x, b.y); r.w = pk2(b.z, b.w);
    return r;
}
__device__ __forceinline__ float dot8(uint4 w, uint4 h, float acc) {
    acc = __builtin_amdgcn_fdot2(__builtin_bit_cast(h2_t, w.x), __builtin_bit_cast(h2_t, h.x), acc, false);
    acc = __builtin_amdgcn_fdot2(__builtin_bit_cast(h2_t, w.y), __builtin_bit_cast(h2_t, h.y), acc, false);
    acc = __builtin_amdgcn_fdot2(__builtin_bit_cast(h2_t, w.z), __builtin_bit_cast(h2_t, h.z), acc, false);
    acc = __builtin_amdgcn_fdot2(__builtin_bit_cast(h2_t, w.w), __builtin_bit_cast(h2_t, h.w), acc, false);
    return acc;
}
__device__ __forceinline__ float fast_sigmoid(float v) {
    return __builtin_amdgcn_rcpf(1.0f + __expf(-v));
}
__device__ __forceinline__ float fast_tanh(float v) {   // 2*sigmoid(2v)-1
    return fmaf(2.0f, __builtin_amdgcn_rcpf(1.0f + __expf(-2.0f * v)), -1.0f);
}

// named f16-packed weight chunks for gate g (6 x uint4 = 48 f16 = this thread's K-half)
#define WROW(g) \
    const float4* wp##g = reinterpret_cast<const float4*>(W_hh + ((g) * HID + j) * HID + p * 48); \
    const uint4 w##g##_0 = cvt8(wp##g[0],  wp##g[1]);  \
    const uint4 w##g##_1 = cvt8(wp##g[2],  wp##g[3]);  \
    const uint4 w##g##_2 = cvt8(wp##g[4],  wp##g[5]);  \
    const uint4 w##g##_3 = cvt8(wp##g[6],  wp##g[7]);  \
    const uint4 w##g##_4 = cvt8(wp##g[8],  wp##g[9]);  \
    const uint4 w##g##_5 = cvt8(wp##g[10], wp##g[11]);

#define DOT6(g, A) \
    A = dot8(w##g##_0, h0, A); A = dot8(w##g##_1, h1, A); \
    A = dot8(w##g##_2, h2, A); A = dot8(w##g##_3, h3, A); \
    A = dot8(w##g##_4, h4, A); A = dot8(w##g##_5, h5, A);

// min-waves/EU = 1: we run 4 waves/block, 1 block/CU -> 1 wave/SIMD. This lifts
// the VGPR budget to 512 so the 96 weight VGPRs stay RESIDENT (R3: launch_bounds
// without it gave VGPR=72 -> weights spilled to scratch, ~15 TB/s L2 reload traffic).
__global__ __launch_bounds__(256, 1)
void lstm_seq_kernel(const float* __restrict__ x,
                     const float* __restrict__ W_ih,
                     const float* __restrict__ W_hh,
                     const float* __restrict__ b_ih,
                     const float* __restrict__ b_hh,
                     const float* __restrict__ W_fc,
                     const float* __restrict__ b_fc,
                     float* __restrict__ out)
{
    const int b   = blockIdx.x;
    const int tid = threadIdx.x;          // 0..255: waves 0-2 = dot workers, wave 3 = FC

    // double-buffered hidden state, f16: [buf][12 x uint4] = 96 halves each
    __shared__ __align__(16) uint4 hq[2][12];

    if (tid < 24) ((uint4*)hq)[tid] = make_uint4(0u, 0u, 0u, 0u);
    __syncthreads();

    if (tid < 192) {
        // -------- worker: unit j = tid>>1, K-half p = tid&1; owns gates i,f,g,o of j --------
        const int j = tid >> 1;
        const int p = tid & 1;

        WROW(0) WROW(1) WROW(2) WROW(3)

        const float wih0 = W_ih[0 * HID + j], bs0 = b_ih[0 * HID + j] + b_hh[0 * HID + j];
        const float wih1 = W_ih[1 * HID + j], bs1 = b_ih[1 * HID + j] + b_hh[1 * HID + j];
        const float wih2 = W_ih[2 * HID + j], bs2 = b_ih[2 * HID + j] + b_hh[2 * HID + j];
        const float wih3 = W_ih[3 * HID + j], bs3 = b_ih[3 * HID + j] + b_hh[3 * HID + j];

        float c  = 0.0f;                  // redundant across the lane pair (identical)
        float xt = x[0 * BATCH + b];

        for (int t = 0; t < T_STEPS; ++t) {
            const int   tn    = (t + 1 < T_STEPS) ? (t + 1) : t;
            const float xnext = x[tn * BATCH + b];            // uniform prefetch

            const uint4* hb = &hq[t & 1][p * 6];
            const uint4 h0 = hb[0], h1 = hb[1], h2 = hb[2];
            const uint4 h3 = hb[3], h4 = hb[4], h5 = hb[5];

            float ai = (p == 0) ? fmaf(xt, wih0, bs0) : 0.0f;
            float af = (p == 0) ? fmaf(xt, wih1, bs1) : 0.0f;
            float ag = (p == 0) ? fmaf(xt, wih2, bs2) : 0.0f;
            float ao = (p == 0) ? fmaf(xt, wih3, bs3) : 0.0f;
            DOT6(0, ai) DOT6(1, af) DOT6(2, ag) DOT6(3, ao)

            // join K-halves across the lane pair (xor-1 -> DPP quad_perm)
            const float si = ai + __shfl_xor(ai, 1);
            const float sf = af + __shfl_xor(af, 1);
            const float sg = ag + __shfl_xor(ag, 1);
            const float so = ao + __shfl_xor(ao, 1);

            const float gi = fast_sigmoid(si);
            const float gf = fast_sigmoid(sf);
            const float gg = fast_tanh(sg);
            const float go = fast_sigmoid(so);
            c = fmaf(gf, c, gi * gg);
            const float hn = go * fast_tanh(c);

            if (p == 0) ((__fp16*)&hq[(t & 1) ^ 1][0])[j] = (__fp16)hn;
            __syncthreads();
            xt = xnext;
        }
    } else {
        // -------- FC wave: out[t-1] = h_t . W_fc + b_fc + x[t-1], one step deferred --------
        const int   lane = tid - 192;
        const float wfa  = W_fc[lane];
        const float wfb  = (lane < 32) ? W_fc[64 + lane] : 0.0f;
        const float bfc  = b_fc[0];

        float xfc = x[b];                                     // x[(t-1)] for t=1
        for (int t = 0; t < T_STEPS; ++t) {
            const float xnext = x[t * BATCH + b];             // becomes xfc for iter t+1
            if (t > 0) {
                const __fp16* hh = (const __fp16*)&hq[t & 1][0];   // h_t
                float s = (float)hh[lane] * wfa;
                if (lane < 32) s = fmaf((float)hh[64 + lane], wfb, s);
                #pragma unroll
                for (int d = 1; d < 64; d <<= 1) s += __shfl_xor(s, d);
                if (lane == 0) out[(t - 1) * BATCH + b] = s + bfc + xfc;
            }
            __syncthreads();
            xfc = xnext;
        }
        {   // final timestep: h_T is in hq[T&1] (T even -> buf 0)
            const __fp16* hh = (const __fp16*)&hq[T_STEPS & 1][0];
            float s = (float)hh[lane] * wfa;
            if (lane < 32) s = fmaf((float)hh[64 + lane], wfb, s);
            #pragma unroll
            for (int d = 1; d < 64; d <<= 1) s += __shfl_xor(s, d);
            if (lane == 0) out[(T_STEPS - 1) * BATCH + b] = s + bfc + xfc;
        }
    }
}

extern "C" void kernel_launch(void* const* d_in, const int* in_sizes, int n_in,
                              void* d_out, int out_size, void* d_ws, size_t ws_size,
                              hipStream_t stream) {
    (void)in_sizes; (void)n_in; (void)out_size; (void)d_ws; (void)ws_size;
    const float* x    = (const float*)d_in[0];
    const float* W_ih = (const float*)d_in[1];
    const float* W_hh = (const float*)d_in[2];
    const float* b_ih = (const float*)d_in[3];
    const float* b_hh = (const float*)d_in[4];
    const float* W_fc = (const float*)d_in[5];
    const float* b_fc = (const float*)d_in[6];
    float* out = (float*)d_out;

    lstm_seq_kernel<<<dim3(BATCH), dim3(256), 0, stream>>>(
        x, W_ih, W_hh, b_ih, b_hh, W_fc, b_fc, out);
}